// Round 7
// baseline (219.005 us; speedup 1.0000x reference)
//
#include <hip/hip_runtime.h>

#define S 7
#define NB 2
#define NC 80
#define NBOX 20
#define CELLS 49
#define CH 85                  // 5 + NC
#define PAIR 170               // NB*CH
#define PER_B 8330             // CELLS*PAIR floats per image
#define NIMG 4096
#define NCELL_TOT (NIMG*CELLS)           // 200704 cells
#define NBOXSLOT (NIMG*CELLS*NB)         // 401408 (cell,box) weight slots
#define N4TOT (NIMG*PER_B/4)             // 8529920 float4s
#define PREP_BLOCKS (NCELL_TOT/256)      // 784 (exact)
#define STREAM_BLOCKS 1960               // 1960*256*17 == N4TOT exactly (no tail)
#define STREAM_ITERS 17
#define L_COORD 5.0f
#define L_NOOBJ 0.5f
#define INV_B (1.0f/4096.0f)

typedef float vfloat4 __attribute__((ext_vector_type(4)));

// ---- block reduce + one device-scope atomic per block (d_out pre-zeroed) ----
__device__ __forceinline__ void block_reduce_atomic(float acc, float* out)
{
    __shared__ float s_wsum[4];
    int tid = threadIdx.x;
    #pragma unroll
    for (int off = 32; off > 0; off >>= 1) acc += __shfl_down(acc, off, 64);
    int lane = tid & 63, wv = tid >> 6;
    if (lane == 0) s_wsum[wv] = acc;
    __syncthreads();
    if (tid == 0)
        atomicAdd(out, (s_wsum[0] + s_wsum[1] + s_wsum[2] + s_wsum[3]) * INV_B);
}

// ---- kernel 1: one thread per cell — winner, weights, all corrections ----
// Stream computes sum wb * p^2 over ALL 85 channels of each box. Prep folds in:
//   obj cell, resp box:  xy/wh full terms, conf (1-2p), class (1-2p_label),
//                        MINUS raw p^2 of channels 0..3 (streamed at w=1).
//   noobj cell:          0.5*(p4^2 + p89^2) directly (wb = 0 for both boxes).
__global__ __launch_bounds__(256) void prep_kernel(
    const float* __restrict__ pred,
    const float* __restrict__ boxes,
    const int*   __restrict__ labels,
    float2*      __restrict__ wb2,      // [NCELL_TOT + pad] (flat = wb[slot*2])
    float*       __restrict__ out)
{
    const int tid   = threadIdx.x;
    const int gcell = blockIdx.x * 256 + tid;        // 0 .. NCELL_TOT-1
    const unsigned img = (unsigned)gcell / (unsigned)CELLS;   // magic-mul
    const int cell  = gcell - (int)img * CELLS;

    // scan this image's 20 boxes DESCENDING: last match == min box index,
    // and its params are captured without a second lookup.
    const float* bx = boxes + (size_t)img * NBOX * 4;
    int winner = NBOX;
    float wx = 0.f, wy = 0.f, wwd = 0.f, wht = 0.f;
    #pragma unroll 4
    for (int b = NBOX - 1; b >= 0; --b) {
        float x1 = bx[4*b], y1 = bx[4*b+1], x2 = bx[4*b+2], y2 = bx[4*b+3];
        float x = (x1 + x2) * 0.5f, y = (y1 + y2) * 0.5f;
        int j = min(max((int)floorf(x * (float)S), 0), S - 1);
        int i = min(max((int)floorf(y * (float)S), 0), S - 1);
        if (i * S + j == cell) {
            winner = b; wx = x; wy = y; wwd = x2 - x1; wht = y2 - y1;
        }
    }

    const float* p = pred + (size_t)gcell * PAIR;
    float acc;
    float2 w;
    if (winner < NBOX) {
        int i = cell / S, j = cell - (cell / S) * S;
        float tx = wx * (float)S - (float)j;
        float ty = wy * (float)S - (float)i;
        float tw = wwd, th = wht;

        float bx1 = tx - tw * 0.5f, by1 = ty - th * 0.5f;
        float bx2 = tx + tw * 0.5f, by2 = ty + th * 0.5f;
        float barea = (bx2 - bx1) * (by2 - by1);
        float iou[2], px[2], py[2], pw[2], ph[2];
        #pragma unroll
        for (int nb = 0; nb < NB; nb++) {
            px[nb] = p[nb * CH + 0]; py[nb] = p[nb * CH + 1];
            pw[nb] = p[nb * CH + 2]; ph[nb] = p[nb * CH + 3];
            float ax1 = px[nb] - pw[nb] * 0.5f, ay1 = py[nb] - ph[nb] * 0.5f;
            float ax2 = px[nb] + pw[nb] * 0.5f, ay2 = py[nb] + ph[nb] * 0.5f;
            float iw = fmaxf(fminf(ax2, bx2) - fmaxf(ax1, bx1), 0.0f);
            float ih = fmaxf(fminf(ay2, by2) - fmaxf(ay1, by1), 0.0f);
            float inter = iw * ih;
            float uni = (ax2 - ax1) * (ay2 - ay1) + barea - inter;
            iou[nb] = inter / (uni + 1e-6f);
        }
        int resp = (iou[1] > iou[0]) ? 1 : 0;
        w = (resp == 0) ? make_float2(1.f, 0.f) : make_float2(0.f, 1.f);

        int lab = labels[img * NBOX + winner];
        float pc = p[resp * CH + 4];
        float pl = p[resp * CH + 5 + lab];
        float dx = px[resp] - tx, dy = py[resp] - ty;
        float dw = sqrtf(fmaxf(pw[resp], 1e-6f)) - sqrtf(fmaxf(tw, 1e-6f));
        float dh = sqrtf(fmaxf(ph[resp], 1e-6f)) - sqrtf(fmaxf(th, 1e-6f));
        acc = L_COORD * (dx * dx + dy * dy + dw * dw + dh * dh)
            + (1.0f - 2.0f * pc)         // (p-1)^2 = p^2 + (1-2p)
            + (1.0f - 2.0f * pl)         // sum(p-onehot)^2 = sum p^2 + (1-2p_l)
            - (px[resp] * px[resp] + py[resp] * py[resp]
             + pw[resp] * pw[resp] + ph[resp] * ph[resp]);  // streamed at w=1
    } else {
        float c0 = p[4], c1 = p[CH + 4];
        acc = L_NOOBJ * (c0 * c0 + c1 * c1);   // wb stays 0 for both boxes
        w = make_float2(0.f, 0.f);
    }
    wb2[gcell] = w;                       // coalesced 8B store
    block_reduce_atomic(acc, out);
}

// ---------------- kernel 2: pure stream, acc += wb[box] * p^2 ----------------
__global__ __launch_bounds__(256) void stream_kernel(
    const vfloat4* __restrict__ p4,
    const float*   __restrict__ wb,
    float*         __restrict__ out)
{
    const int tid  = threadIdx.x;
    const int base = blockIdx.x * (STREAM_ITERS * 256);

    float acc = 0.0f;
    #pragma unroll
    for (int k = 0; k < STREAM_ITERS; ++k) {
        int e = base + k * 256 + tid;
        vfloat4 v = p4[e];
        unsigned ff = 4u * (unsigned)e;
        unsigned bi = ff / 85u;                 // magic-mul
        int r85 = (int)(ff - bi * 85u);
        int thr = 85 - r85;                     // element k uses next box iff k >= thr
        float wa = wb[bi];
        float wn = wb[bi + 1];                  // speculative; padded table
        float w1 = (1 < thr) ? wa : wn;
        float w2 = (2 < thr) ? wa : wn;
        float w3 = (3 < thr) ? wa : wn;
        acc += wa * (v.x * v.x);
        acc += w1 * (v.y * v.y);
        acc += w2 * (v.z * v.z);
        acc += w3 * (v.w * v.w);
    }
    block_reduce_atomic(acc, out);
}

extern "C" void kernel_launch(void* const* d_in, const int* in_sizes, int n_in,
                              void* d_out, int out_size, void* d_ws, size_t ws_size,
                              hipStream_t stream) {
    const float* pred   = (const float*)d_in[0];
    const float* boxes  = (const float*)d_in[1];
    const int*   labels = (const int*)d_in[2];
    float* out = (float*)d_out;

    float* wb = (float*)d_ws;   // [NBOXSLOT + pad] flat weight table

    hipMemsetAsync(d_out, 0, sizeof(float) * out_size, stream);
    prep_kernel<<<PREP_BLOCKS, 256, 0, stream>>>(pred, boxes, labels,
                                                 (float2*)wb, out);
    stream_kernel<<<STREAM_BLOCKS, 256, 0, stream>>>((const vfloat4*)pred, wb, out);
}